// Round 4
// baseline (363.285 us; speedup 1.0000x reference)
//
#include <hip/hip_runtime.h>
#include <stdint.h>

typedef __attribute__((ext_vector_type(4))) int i32x4;
typedef __attribute__((ext_vector_type(8))) int i32x8;
typedef __attribute__((ext_vector_type(16))) float f32x16;

#define BM 128
#define BN 128
// Quantized operands live in global memory in MFMA-FRAGMENT ORDER:
//   fragment = 32 consecutive K-elements of one row, packed to 16 B (fp4 signs).
//   index16(row, k32) = ((row>>5)*kbT + (k32>>2))*128 + (k32&3)*32 + (row&31)
//   where k32 = k/32, kbT = K/128 (64-B K-tiles per row).
// Producer (quant) iterates the OUTPUT index o (u32 granularity, o = fi*4 + w)
// and decodes (row, k32, w) via the inverse map -> stores lane-consecutive
// (coalesced) AND reads land as 128-B contiguous row chunks per 4-lane quad.

// fp4 e2m1 signs: +1 = 0x2, -1 = 0xA, 0 = 0x0 (matches jnp.sign exactly)
__device__ __forceinline__ uint32_t nib4(float v) {
  return v > 0.f ? 0x2u : (v < 0.f ? 0xAu : 0u);
}

// 8 fp32 -> 8 nibbles in one u32 (element j -> nibble j, low nibble first)
__device__ __forceinline__ uint32_t pack8(float4 a, float4 b) {
  return nib4(a.x) | (nib4(a.y) << 4) | (nib4(a.z) << 8) | (nib4(a.w) << 12) |
         (nib4(b.x) << 16) | (nib4(b.y) << 20) | (nib4(b.z) << 24) | (nib4(b.w) << 28);
}

__device__ __forceinline__ float abs4(float4 v) {
  return fabsf(v.x) + fabsf(v.y) + fabsf(v.z) + fabsf(v.w);
}

// ---------------- fused quantize -> fragment-ordered fp4 ----------------
// Blocks [0, wBlocks): weights. Block owns 32-row panel rb: full rows ->
//   block-local mean|w| scale (quad shfl reduce + LDS atomic per 32-elem chunk).
// Blocks [wBlocks, wBlocks+xBlocks): x. 4 output-u32 per thread, inverse-decode.
// Inverse map (o = u32 index): fi=o>>2, w=o&3, p2=fi&127, g=fi>>7,
//   rowblk=g>>kbShift, kbblk=g&(kbT-1), row=rowblk*32+(p2&31), k32=kbblk*4+(p2>>5).
// Lanes 0..3 share a row and read 128 B contiguous; stores fully coalesced.
__global__ __launch_bounds__(256) void quant_fused_kernel(
    const float4* __restrict__ x, uint32_t* __restrict__ xq,
    const float4* __restrict__ w, uint32_t* __restrict__ wq,
    float* __restrict__ scale, int wBlocks, int K, int kbShift) {
  const int t = threadIdx.x;
  const int b = blockIdx.x;
  const int kbT = K >> 7;
  const int K4 = K >> 2;  // float4s per row

  if (b < wBlocks) {
    // ---- weight panel rb: rows [rb*32, rb*32+32), all K ----
    const int rb = b;
    __shared__ float accum[32];
    if (t < 32) accum[t] = 0.f;
    __syncthreads();
    // 16384 u32 outputs per panel, 64 iterations x 256 threads
    for (int it = 0; it < 64; ++it) {
      const int ol = it * 256 + t;               // 0..16383
      const uint32_t o = (uint32_t)rb * 16384u + ol;
      const int fi_lo = (ol >> 2) & 127;         // p2
      const int wrd = ol & 3;
      const int q = ol >> 9;                     // kbblk (0..31)
      const int rloc = fi_lo & 31;
      const int k32 = q * 4 + (fi_lo >> 5);
      const float4* src = w + (size_t)(rb * 32 + rloc) * K4 + k32 * 8 + wrd * 2;
      float4 a = src[0], c = src[1];
      wq[o] = pack8(a, c);
      float asum = abs4(a) + abs4(c);
      asum += __shfl_xor(asum, 1);
      asum += __shfl_xor(asum, 2);
      if ((t & 3) == 0) atomicAdd(&accum[rloc], asum);
    }
    __syncthreads();
    if (t < 32) scale[rb * 32 + t] = accum[t] * (1.0f / (float)K);
  } else {
    // ---- x: 1024 output u32 per block, 4 per thread ----
    const size_t base = (size_t)(b - wBlocks) * 1024;
#pragma unroll
    for (int j = 0; j < 4; ++j) {
      const size_t o = base + (size_t)j * 256 + t;
      const int wrd = (int)(o & 3);
      const size_t fi = o >> 2;
      const int p2 = (int)(fi & 127);
      const size_t g = fi >> 7;
      const size_t rowblk = g >> kbShift;
      const int kbblk = (int)(g & (kbT - 1));
      const size_t row = rowblk * 32 + (p2 & 31);
      const int k32 = kbblk * 4 + (p2 >> 5);
      const float4* src = x + row * K4 + k32 * 8 + wrd * 2;
      float4 a = src[0], c = src[1];
      xq[o] = pack8(a, c);  // lane-consecutive o -> fully coalesced
    }
  }
}

// async global->LDS, 16B per lane (wave-uniform base + lane*16)
__device__ __forceinline__ void load16(const uint8_t* g, uint8_t* l) {
  __builtin_amdgcn_global_load_lds(
      (const __attribute__((address_space(1))) uint32_t*)(uintptr_t)g,
      (__attribute__((address_space(3))) uint32_t*)(uintptr_t)l,
      16, 0, 0);
}

// ---------------- GEMM: C[m,n] = scale[n] * sum_k A[m,k]*B[n,k] ----------------
// A, B in fragment order (see header comment). mfma_scale 32x32x64 f8f6f4, FMT=4,
// scales pinned to 1.0 (e8m0 0x7F). fp32 accumulate exact for +-1 sums.
// 256 threads = 4 waves in 2x2; each wave does 64x64 via 2x2 of 32x32 tiles.
__global__ __launch_bounds__(256, 3) void gemm_bt_kernel(
    const uint8_t* __restrict__ A, const uint8_t* __restrict__ B,
    const float* __restrict__ scale, float* __restrict__ C,
    int M, int N, int K) {
  __shared__ __align__(16) uint8_t As[BM * 64];  // 4 groups x 128 frags x 16 B
  __shared__ __align__(16) uint8_t Bs[BN * 64];

  const int tid = threadIdx.x;
  const int lane = tid & 63;
  const int wave = tid >> 6;
  const int waveM = wave & 1;
  const int waveN = wave >> 1;
  const int kbT = K >> 7;  // K-tile iterations (64 B of K per iter)

  // XCD-aware bijective swizzle (nwg = gridDim.x*gridDim.y, divisible by 8)
  const int nwg = gridDim.x * gridDim.y;
  const int id = blockIdx.y * gridDim.x + blockIdx.x;
  const int swz = (id & 7) * (nwg >> 3) + (id >> 3);
  const int bx = swz % gridDim.x;
  const int by = swz / gridDim.x;

  // staging: wave w owns 32-row group w; 2 contiguous 1024-B loads per K-iter
  const uint8_t* aG = A + ((size_t)(by * 4 + wave) * kbT) * 2048 + lane * 16;
  const uint8_t* bG = B + ((size_t)(bx * 4 + wave) * kbT) * 2048 + lane * 16;
  uint8_t* aL = As + wave * 2048 + lane * 16;
  uint8_t* bL = Bs + wave * 2048 + lane * 16;

  // fragment reads: group (2*waveM+mi), p2 = s*64 + lane  ->  lane-linear
  const uint8_t* aF = As + waveM * 4096 + lane * 16;
  const uint8_t* bF = Bs + waveN * 4096 + lane * 16;

  f32x16 acc[2][2] = {};
  // persistent v8i32 operands; high 4 regs stay zero (fp4 uses low 4 only)
  i32x8 aop[2] = {}, bop[2] = {};

  for (int i = 0; i < kbT; ++i) {
    __syncthreads();  // previous iter's LDS reads done before overwrite
    const size_t o = (size_t)i * 2048;
    load16(aG + o, aL);
    load16(aG + o + 1024, aL + 1024);
    load16(bG + o, bL);
    load16(bG + o + 1024, bL + 1024);
    __syncthreads();  // staging complete (vmcnt drained before barrier)

#pragma unroll
    for (int s = 0; s < 2; ++s) {  // two K=64 MFMA steps per 64-B row tile
#pragma unroll
      for (int mi = 0; mi < 2; ++mi) {
        i32x4 t4 = *(const i32x4*)(aF + mi * 2048 + s * 1024);
        aop[mi].s0 = t4.x; aop[mi].s1 = t4.y; aop[mi].s2 = t4.z; aop[mi].s3 = t4.w;
      }
#pragma unroll
      for (int ni = 0; ni < 2; ++ni) {
        i32x4 t4 = *(const i32x4*)(bF + ni * 2048 + s * 1024);
        bop[ni].s0 = t4.x; bop[ni].s1 = t4.y; bop[ni].s2 = t4.z; bop[ni].s3 = t4.w;
      }
#pragma unroll
      for (int mi = 0; mi < 2; ++mi)
#pragma unroll
        for (int ni = 0; ni < 2; ++ni)
          acc[mi][ni] = __builtin_amdgcn_mfma_scale_f32_32x32x64_f8f6f4(
              aop[mi], bop[ni], acc[mi][ni],
              /*cbsz=fp4*/ 4, /*blgp=fp4*/ 4,
              /*opsel_a*/ 0, 0x7f7f7f7f, /*opsel_b*/ 0, 0x7f7f7f7f);
    }
  }

  // epilogue: 32x32 C/D layout col=lane&31, row=(reg&3)+8*(reg>>2)+4*(lane>>5)
  const int cCol = bx * BN + waveN * 64 + (lane & 31);
  const int cRowBase = by * BM + waveM * 64 + 4 * (lane >> 5);
  float sc[2];
#pragma unroll
  for (int ni = 0; ni < 2; ++ni) sc[ni] = scale[cCol + ni * 32];
#pragma unroll
  for (int mi = 0; mi < 2; ++mi)
#pragma unroll
    for (int ni = 0; ni < 2; ++ni)
#pragma unroll
      for (int r = 0; r < 16; ++r) {
        int row = cRowBase + mi * 32 + (r & 3) + 8 * (r >> 2);
        C[(size_t)row * N + cCol + ni * 32] = acc[mi][ni][r] * sc[ni];
      }
}

// ---------------- fallback (only if ws too small): exact, slow ----------------
__global__ void fallback_gemm(const float* __restrict__ X, const float* __restrict__ W,
                              float* __restrict__ C, int M, int N, int K) {
  __shared__ float xs[16][65];
  __shared__ float ws[16][65];
  __shared__ float wabs[256];
  __shared__ float scl[16];
  const int tx = threadIdx.x, ty = threadIdx.y;
  const int t = ty * 16 + tx;
  float acc = 0.f, wa = 0.f;
  for (int k0 = 0; k0 < K; k0 += 64) {
    __syncthreads();
#pragma unroll
    for (int j = 0; j < 4; ++j) {
      int e = t * 4 + j;
      int r = e >> 6, c = e & 63;
      float xv = X[(size_t)(blockIdx.y * 16 + r) * K + k0 + c];
      xs[r][c] = xv > 0.f ? 1.f : (xv < 0.f ? -1.f : 0.f);
      float wv = W[(size_t)(blockIdx.x * 16 + r) * K + k0 + c];
      ws[r][c] = wv > 0.f ? 1.f : (wv < 0.f ? -1.f : 0.f);
      wa += fabsf(wv);
    }
    __syncthreads();
#pragma unroll 8
    for (int k = 0; k < 64; ++k) acc += xs[ty][k] * ws[tx][k];
  }
  wabs[t] = wa;
  __syncthreads();
  for (int s2 = 8; s2 > 0; s2 >>= 1) {
    if (tx < s2) wabs[t] += wabs[t + s2];
    __syncthreads();
  }
  if (tx == 0) scl[ty] = wabs[t] / (float)K;
  __syncthreads();
  C[(size_t)(blockIdx.y * 16 + ty) * N + (blockIdx.x * 16 + tx)] = acc * scl[tx];
}

extern "C" void kernel_launch(void* const* d_in, const int* in_sizes, int n_in,
                              void* d_out, int out_size, void* d_ws, size_t ws_size,
                              hipStream_t stream) {
  const float* x = (const float*)d_in[0];
  const float* w = (const float*)d_in[1];
  float* out = (float*)d_out;

  const int K = 4096;
  const int N = in_sizes[1] / K;  // 4096
  const int M = in_sizes[0] / K;  // 8192

  size_t need = (size_t)M * (K / 2) + (size_t)N * (K / 2) + (size_t)N * sizeof(float);
  if (ws_size >= need) {
    uint8_t* Xq = (uint8_t*)d_ws;
    uint8_t* Wq = Xq + (size_t)M * (K / 2);
    float* scale = (float*)(Wq + (size_t)N * (K / 2));

    const int kbT = K >> 7;             // 32
    const int kbShift = __builtin_ctz(kbT);
    const int wBlocks = N / 32;         // 128 panels, 32 rows each
    const int xBlocks = (int)(((size_t)M * K / 8) / 1024);  // 4096
    quant_fused_kernel<<<wBlocks + xBlocks, 256, 0, stream>>>(
        (const float4*)x, (uint32_t*)Xq, (const float4*)w, (uint32_t*)Wq,
        scale, wBlocks, K, kbShift);

    dim3 grid(N / BN, M / BM);
    gemm_bt_kernel<<<grid, 256, 0, stream>>>(Xq, Wq, scale, out, M, N, K);
  } else {
    dim3 grid(N / 16, M / 16);
    fallback_gemm<<<grid, dim3(16, 16), 0, stream>>>(x, w, out, M, N, K);
  }
}